// Round 1
// baseline (410.740 us; speedup 1.0000x reference)
//
#include <hip/hip_runtime.h>

// Elementwise: y = (x + 1) * 2 / 3 ; out = (y > 0) ? y - 5 : y
// 8192*8192 fp32 = 67,108,864 elements = 16,777,216 float4 quads.
// Memory-bound: 512 MB total traffic -> ~81 us at 6.3 TB/s achievable.

__global__ __launch_bounds__(256) void elementwise_kernel(
    const float4* __restrict__ x, float4* __restrict__ out, int n4) {
    int i = blockIdx.x * blockDim.x + threadIdx.x;
    if (i >= n4) return;
    float4 v = x[i];
    float4 r;
    {
        float y = ((v.x + 1.0f) * 2.0f) / 3.0f;
        r.x = (y > 0.0f) ? (y - 5.0f) : y;
    }
    {
        float y = ((v.y + 1.0f) * 2.0f) / 3.0f;
        r.y = (y > 0.0f) ? (y - 5.0f) : y;
    }
    {
        float y = ((v.z + 1.0f) * 2.0f) / 3.0f;
        r.z = (y > 0.0f) ? (y - 5.0f) : y;
    }
    {
        float y = ((v.w + 1.0f) * 2.0f) / 3.0f;
        r.w = (y > 0.0f) ? (y - 5.0f) : y;
    }
    out[i] = r;
}

extern "C" void kernel_launch(void* const* d_in, const int* in_sizes, int n_in,
                              void* d_out, int out_size, void* d_ws, size_t ws_size,
                              hipStream_t stream) {
    const float* x = (const float*)d_in[0];
    float* out = (float*)d_out;
    int n = in_sizes[0];          // 67,108,864 — divisible by 4
    int n4 = n / 4;               // 16,777,216
    int block = 256;
    int grid = (n4 + block - 1) / block;  // 65,536 blocks
    elementwise_kernel<<<grid, block, 0, stream>>>(
        (const float4*)x, (float4*)out, n4);
}